// Round 2
// baseline (4780.950 us; speedup 1.0000x reference)
//
#include <hip/hip_runtime.h>

// Shapes: B=64, N=197, C=768, H=12, hd=64
// inputs: x[64,197,768] f32, table[730,12] f32, w_qkv[2304,768] f32,
//         w_proj[768,768] f32, b_proj[768] f32, rel_index[197,197] i32
// out: [64,197,768] f32

#define NB   64
#define NN   197
#define NC   768
#define NH   12
#define HD   64
#define MM   (NB*NN)      // 12608

__device__ inline unsigned int bf16_rne(float f) {
    unsigned int u = __float_as_uint(f);
    return (u + 0x7fffu + ((u >> 16) & 1u)) >> 16;
}
__device__ inline unsigned int pack2_bf16(float lo, float hi) {
    return bf16_rne(lo) | (bf16_rne(hi) << 16);
}

// ---------------------------------------------------------------------------
// GEMM1: Y = X[M,768] * Wqkv[2304,768]^T -> scatter q/k/v [B,H,N,hd]
// 128x128 tile, TK=16, 256 threads, 8x8 per thread.
// B-side LDS chunk-swizzled (chunk' = chunk ^ (chunk>>3)) -> 2-way max reads.
// ---------------------------------------------------------------------------
__global__ __launch_bounds__(256, 2) void gemm_qkv_kernel(
    const float* __restrict__ X, const float* __restrict__ W,
    float* __restrict__ qb, float* __restrict__ kb, float* __restrict__ vb)
{
    __shared__ float As[16][132];   // As[k][m]
    __shared__ float Bs[16][132];   // Bs[k][n'] (swizzled chunks)
    const int tid = threadIdx.x;
    const int m0 = blockIdx.x * 128;
    const int n0 = blockIdx.y * 128;

    // staging map: load1 covers rows 0..63 (4 lanes/row along k), load2 rows 64..127
    const int r1 = tid >> 2;               // 0..63
    const int c1 = (tid & 3) << 2;         // k-chunk {0,4,8,12}
    int am1 = m0 + r1;        if (am1 >= MM) am1 = MM - 1;
    int am2 = m0 + r1 + 64;   if (am2 >= MM) am2 = MM - 1;
    const float* Ap1 = X + (size_t)am1 * NC + c1;
    const float* Ap2 = X + (size_t)am2 * NC + c1;
    const float* Bp1 = W + (size_t)(n0 + r1) * NC + c1;
    const float* Bp2 = W + (size_t)(n0 + r1 + 64) * NC + c1;

    // swizzled store columns for B rows r1 and r1+64
    const int ch1 = r1 >> 2,  ch2 = (r1 + 64) >> 2;
    const int bcol1 = ((ch1 ^ (ch1 >> 3)) << 2) + (r1 & 3);
    const int bcol2 = ((ch2 ^ (ch2 >> 3)) << 2) + (r1 & 3);

    const int tx = tid & 15;               // col group of 8
    const int ty = tid >> 4;               // row group of 8
    // swizzled read chunks for cols tx*8 .. tx*8+7
    const int rcA = (tx << 1), rcB = (tx << 1) + 1;
    const int bcA = ((rcA ^ (rcA >> 3)) << 2);
    const int bcB = ((rcB ^ (rcB >> 3)) << 2);

    float acc[8][8] = {};

    for (int k0 = 0; k0 < NC; k0 += 16) {
        float4 a0 = *(const float4*)(Ap1 + k0);
        float4 a1 = *(const float4*)(Ap2 + k0);
        float4 b0 = *(const float4*)(Bp1 + k0);
        float4 b1 = *(const float4*)(Bp2 + k0);
        __syncthreads();
        As[c1+0][r1] = a0.x; As[c1+1][r1] = a0.y; As[c1+2][r1] = a0.z; As[c1+3][r1] = a0.w;
        As[c1+0][r1+64] = a1.x; As[c1+1][r1+64] = a1.y; As[c1+2][r1+64] = a1.z; As[c1+3][r1+64] = a1.w;
        Bs[c1+0][bcol1] = b0.x; Bs[c1+1][bcol1] = b0.y; Bs[c1+2][bcol1] = b0.z; Bs[c1+3][bcol1] = b0.w;
        Bs[c1+0][bcol2] = b1.x; Bs[c1+1][bcol2] = b1.y; Bs[c1+2][bcol2] = b1.z; Bs[c1+3][bcol2] = b1.w;
        __syncthreads();
        #pragma unroll
        for (int kk = 0; kk < 16; kk++) {
            float4 av0 = *(const float4*)&As[kk][ty << 3];
            float4 av1 = *(const float4*)&As[kk][(ty << 3) + 4];
            float4 bv0 = *(const float4*)&Bs[kk][bcA];
            float4 bv1 = *(const float4*)&Bs[kk][bcB];
            float a[8] = {av0.x, av0.y, av0.z, av0.w, av1.x, av1.y, av1.z, av1.w};
            float b[8] = {bv0.x, bv0.y, bv0.z, bv0.w, bv1.x, bv1.y, bv1.z, bv1.w};
            #pragma unroll
            for (int i = 0; i < 8; i++)
                #pragma unroll
                for (int j = 0; j < 8; j++)
                    acc[i][j] = fmaf(a[i], b[j], acc[i][j]);
        }
    }

    // epilogue: cols n0+tx*8+j all in one (t,h) since tx*8 is 8-aligned in a 64-block
    const int c0 = n0 + (tx << 3);
    const int tq = c0 / NC;
    const int hh = (c0 % NC) / HD;
    const int d0 = c0 % HD;
    float* dst = (tq == 0) ? qb : (tq == 1) ? kb : vb;
    const float scale = (tq == 0) ? 0.125f : 1.0f;
    #pragma unroll
    for (int i = 0; i < 8; i++) {
        int m = m0 + (ty << 3) + i;
        if (m < MM) {
            int b_ = m / NN;
            int n  = m - b_ * NN;
            float* p = &dst[(((size_t)b_ * NH + hh) * NN + n) * HD + d0];
            float4 v0 = {acc[i][0]*scale, acc[i][1]*scale, acc[i][2]*scale, acc[i][3]*scale};
            float4 v1 = {acc[i][4]*scale, acc[i][5]*scale, acc[i][6]*scale, acc[i][7]*scale};
            *(float4*)p = v0;
            *(float4*)(p + 4) = v1;
        }
    }
}

// ---------------------------------------------------------------------------
// GEMM2: out = A[M,768] * Wproj[768,768]^T + bias  (same structure)
// ---------------------------------------------------------------------------
__global__ __launch_bounds__(256, 2) void gemm_proj_kernel(
    const float* __restrict__ A, const float* __restrict__ W,
    const float* __restrict__ bias, float* __restrict__ out)
{
    __shared__ float As[16][132];
    __shared__ float Bs[16][132];
    const int tid = threadIdx.x;
    const int m0 = blockIdx.x * 128;
    const int n0 = blockIdx.y * 128;

    const int r1 = tid >> 2;
    const int c1 = (tid & 3) << 2;
    int am1 = m0 + r1;        if (am1 >= MM) am1 = MM - 1;
    int am2 = m0 + r1 + 64;   if (am2 >= MM) am2 = MM - 1;
    const float* Ap1 = A + (size_t)am1 * NC + c1;
    const float* Ap2 = A + (size_t)am2 * NC + c1;
    const float* Bp1 = W + (size_t)(n0 + r1) * NC + c1;
    const float* Bp2 = W + (size_t)(n0 + r1 + 64) * NC + c1;

    const int ch1 = r1 >> 2,  ch2 = (r1 + 64) >> 2;
    const int bcol1 = ((ch1 ^ (ch1 >> 3)) << 2) + (r1 & 3);
    const int bcol2 = ((ch2 ^ (ch2 >> 3)) << 2) + (r1 & 3);

    const int tx = tid & 15;
    const int ty = tid >> 4;
    const int rcA = (tx << 1), rcB = (tx << 1) + 1;
    const int bcA = ((rcA ^ (rcA >> 3)) << 2);
    const int bcB = ((rcB ^ (rcB >> 3)) << 2);

    float acc[8][8] = {};

    for (int k0 = 0; k0 < NC; k0 += 16) {
        float4 a0 = *(const float4*)(Ap1 + k0);
        float4 a1 = *(const float4*)(Ap2 + k0);
        float4 b0 = *(const float4*)(Bp1 + k0);
        float4 b1 = *(const float4*)(Bp2 + k0);
        __syncthreads();
        As[c1+0][r1] = a0.x; As[c1+1][r1] = a0.y; As[c1+2][r1] = a0.z; As[c1+3][r1] = a0.w;
        As[c1+0][r1+64] = a1.x; As[c1+1][r1+64] = a1.y; As[c1+2][r1+64] = a1.z; As[c1+3][r1+64] = a1.w;
        Bs[c1+0][bcol1] = b0.x; Bs[c1+1][bcol1] = b0.y; Bs[c1+2][bcol1] = b0.z; Bs[c1+3][bcol1] = b0.w;
        Bs[c1+0][bcol2] = b1.x; Bs[c1+1][bcol2] = b1.y; Bs[c1+2][bcol2] = b1.z; Bs[c1+3][bcol2] = b1.w;
        __syncthreads();
        #pragma unroll
        for (int kk = 0; kk < 16; kk++) {
            float4 av0 = *(const float4*)&As[kk][ty << 3];
            float4 av1 = *(const float4*)&As[kk][(ty << 3) + 4];
            float4 bv0 = *(const float4*)&Bs[kk][bcA];
            float4 bv1 = *(const float4*)&Bs[kk][bcB];
            float a[8] = {av0.x, av0.y, av0.z, av0.w, av1.x, av1.y, av1.z, av1.w};
            float b[8] = {bv0.x, bv0.y, bv0.z, bv0.w, bv1.x, bv1.y, bv1.z, bv1.w};
            #pragma unroll
            for (int i = 0; i < 8; i++)
                #pragma unroll
                for (int j = 0; j < 8; j++)
                    acc[i][j] = fmaf(a[i], b[j], acc[i][j]);
        }
    }

    const int c0 = n0 + (tx << 3);
    const float4 bi0 = *(const float4*)&bias[c0];
    const float4 bi1 = *(const float4*)&bias[c0 + 4];
    #pragma unroll
    for (int i = 0; i < 8; i++) {
        int m = m0 + (ty << 3) + i;
        if (m < MM) {
            float4 v0 = {acc[i][0]+bi0.x, acc[i][1]+bi0.y, acc[i][2]+bi0.z, acc[i][3]+bi0.w};
            float4 v1 = {acc[i][4]+bi1.x, acc[i][5]+bi1.y, acc[i][6]+bi1.z, acc[i][7]+bi1.w};
            *(float4*)&out[(size_t)m * NC + c0] = v0;
            *(float4*)&out[(size_t)m * NC + c0 + 4] = v1;
        }
    }
}

// ---------------------------------------------------------------------------
// Attention v2: grid (768, 4), 256 threads (4 waves).
// K staged in LDS as bf16 (25.2 KB, chunk-XOR swizzled). Q via L1 broadcast
// loads. Worker = blockIdx.y*4 + wave handles query tiles t, t+16, t+32.
// LDS total 38 KB -> 4 blocks/CU -> 16 waves/CU.
// ---------------------------------------------------------------------------
__global__ __launch_bounds__(256, 4) void attn_kernel(
    const float* __restrict__ qb, const float* __restrict__ kb,
    const float* __restrict__ vb, const float* __restrict__ table,
    const int* __restrict__ rel_index, float* __restrict__ ab)
{
    __shared__ unsigned short Kbf[NN * HD];   // bf16; 16B chunk c stored at c^(m&7)
    __shared__ float Psh[4][4][200];          // per wave: 4 queries x keys

    const int bh = blockIdx.x;
    const int b = bh / NH, h = bh % NH;
    const int tid = threadIdx.x;
    const int w = tid >> 6, lane = tid & 63;
    const size_t base = (size_t)bh * (NN * HD);
    const float* kg = kb + base;
    const float* vg = vb + base;
    const float* qg = qb + base;

    // stage K -> bf16 LDS (RNE), swizzled
    for (int i = tid; i < NN * 8; i += 256) {
        int m = i >> 3, c = i & 7;
        const float* src = kg + m * HD + (c << 3);
        float4 f0 = *(const float4*)(src);
        float4 f1 = *(const float4*)(src + 4);
        uint4 u;
        u.x = pack2_bf16(f0.x, f0.y);
        u.y = pack2_bf16(f0.z, f0.w);
        u.z = pack2_bf16(f1.x, f1.y);
        u.w = pack2_bf16(f1.z, f1.w);
        *(uint4*)&Kbf[m * HD + ((c ^ (m & 7)) << 3)] = u;
    }
    __syncthreads();

    float* pw0 = Psh[w][0]; float* pw1 = Psh[w][1];
    float* pw2 = Psh[w][2]; float* pw3 = Psh[w][3];

    const int worker = blockIdx.y * 4 + w;    // 0..15

    for (int t = worker; t < 50; t += 16) {
        int nq[4];
        #pragma unroll
        for (int qi = 0; qi < 4; qi++) {
            int n = t * 4 + qi; nq[qi] = (n > 196) ? 196 : n;
        }

        // scores init with relative-position bias; invalid keys -> -1e30
        float s[4][4];
        #pragma unroll
        for (int qi = 0; qi < 4; qi++) {
            const int* ri = rel_index + nq[qi] * NN;
            #pragma unroll
            for (int j = 0; j < 4; j++) {
                int m = lane + 64 * j;
                s[qi][j] = (m < NN) ? table[ri[m] * NH + h] : -1e30f;
            }
        }
        int mrow[4];
        #pragma unroll
        for (int j = 0; j < 4; j++) {
            int m = lane + 64 * j; mrow[j] = (m < NN) ? m : 196;
        }

        // QK^T: 8 steps of 8 d's
        #pragma unroll
        for (int d8 = 0; d8 < 8; d8++) {
            float4 q0[4], q1[4];
            #pragma unroll
            for (int qi = 0; qi < 4; qi++) {
                const float* qp = qg + nq[qi] * HD + (d8 << 3);
                q0[qi] = *(const float4*)(qp);
                q1[qi] = *(const float4*)(qp + 4);
            }
            #pragma unroll
            for (int j = 0; j < 4; j++) {
                uint4 ku = *(const uint4*)&Kbf[mrow[j] * HD + ((d8 ^ (mrow[j] & 7)) << 3)];
                float k0 = __uint_as_float(ku.x << 16);
                float k1 = __uint_as_float(ku.x & 0xffff0000u);
                float k2 = __uint_as_float(ku.y << 16);
                float k3 = __uint_as_float(ku.y & 0xffff0000u);
                float k4 = __uint_as_float(ku.z << 16);
                float k5 = __uint_as_float(ku.z & 0xffff0000u);
                float k6 = __uint_as_float(ku.w << 16);
                float k7 = __uint_as_float(ku.w & 0xffff0000u);
                #pragma unroll
                for (int qi = 0; qi < 4; qi++) {
                    float acc = s[qi][j];
                    acc = fmaf(q0[qi].x, k0, acc);
                    acc = fmaf(q0[qi].y, k1, acc);
                    acc = fmaf(q0[qi].z, k2, acc);
                    acc = fmaf(q0[qi].w, k3, acc);
                    acc = fmaf(q1[qi].x, k4, acc);
                    acc = fmaf(q1[qi].y, k5, acc);
                    acc = fmaf(q1[qi].z, k6, acc);
                    acc = fmaf(q1[qi].w, k7, acc);
                    s[qi][j] = acc;
                }
            }
        }

        // softmax per query row across 64 lanes x 4 slots
        #pragma unroll
        for (int qi = 0; qi < 4; qi++) {
            float mx = fmaxf(fmaxf(s[qi][0], s[qi][1]), fmaxf(s[qi][2], s[qi][3]));
            #pragma unroll
            for (int off = 32; off > 0; off >>= 1)
                mx = fmaxf(mx, __shfl_xor(mx, off));
            float e[4];
            e[0] = __expf(s[qi][0] - mx); e[1] = __expf(s[qi][1] - mx);
            e[2] = __expf(s[qi][2] - mx); e[3] = __expf(s[qi][3] - mx);
            float sum = (e[0] + e[1]) + (e[2] + e[3]);
            #pragma unroll
            for (int off = 32; off > 0; off >>= 1)
                sum += __shfl_xor(sum, off);
            float inv = 1.0f / sum;
            float* pw = Psh[w][qi];
            #pragma unroll
            for (int j = 0; j < 4; j++) {
                int m = lane + 64 * j;
                if (m < 200) pw[m] = e[j] * inv;   // m in [197,200) -> exp(-1e30)=0
            }
        }

        // P·V: lane = output d; V coalesced from global (L2-resident)
        float o[4] = {0.f, 0.f, 0.f, 0.f};
        #pragma unroll 2
        for (int s4 = 0; s4 < 49; s4++) {
            const int mb = s4 * 4;
            float4 P0 = *(const float4*)&pw0[mb];
            float4 P1 = *(const float4*)&pw1[mb];
            float4 P2 = *(const float4*)&pw2[mb];
            float4 P3 = *(const float4*)&pw3[mb];
            const float* vp = vg + mb * HD + lane;
            float v0 = vp[0], v1 = vp[64], v2 = vp[128], v3 = vp[192];
            o[0] = fmaf(P0.x, v0, fmaf(P0.y, v1, fmaf(P0.z, v2, fmaf(P0.w, v3, o[0]))));
            o[1] = fmaf(P1.x, v0, fmaf(P1.y, v1, fmaf(P1.z, v2, fmaf(P1.w, v3, o[1]))));
            o[2] = fmaf(P2.x, v0, fmaf(P2.y, v1, fmaf(P2.z, v2, fmaf(P2.w, v3, o[2]))));
            o[3] = fmaf(P3.x, v0, fmaf(P3.y, v1, fmaf(P3.z, v2, fmaf(P3.w, v3, o[3]))));
        }
        {   // tail key m = 196
            float v0 = vg[196 * HD + lane];
            o[0] = fmaf(pw0[196], v0, o[0]);
            o[1] = fmaf(pw1[196], v0, o[1]);
            o[2] = fmaf(pw2[196], v0, o[2]);
            o[3] = fmaf(pw3[196], v0, o[3]);
        }

        // write attn output in [B,N,C] layout for proj GEMM
        #pragma unroll
        for (int qi = 0; qi < 4; qi++) {
            int n = t * 4 + qi;
            if (n < NN) ab[((size_t)b * NN + n) * NC + h * HD + lane] = o[qi];
        }
    }
}

// ---------------------------------------------------------------------------
extern "C" void kernel_launch(void* const* d_in, const int* in_sizes, int n_in,
                              void* d_out, int out_size, void* d_ws, size_t ws_size,
                              hipStream_t stream)
{
    const float* x        = (const float*)d_in[0];
    const float* table    = (const float*)d_in[1];
    const float* w_qkv    = (const float*)d_in[2];
    const float* w_proj   = (const float*)d_in[3];
    const float* b_proj   = (const float*)d_in[4];
    const int*   rel_idx  = (const int*)d_in[5];
    float* out = (float*)d_out;

    const size_t SZ = (size_t)NB * NH * NN * HD;   // 9,682,944 floats
    float* qb = (float*)d_ws;
    float* kb = qb + SZ;
    float* vb = kb + SZ;
    float* ab = vb + SZ;                            // [B,N,C]

    gemm_qkv_kernel<<<dim3(99, 18), 256, 0, stream>>>(x, w_qkv, qb, kb, vb);
    attn_kernel<<<dim3(NB * NH, 4), 256, 0, stream>>>(qb, kb, vb, table, rel_idx, ab);
    gemm_proj_kernel<<<dim3(99, 6), 256, 0, stream>>>(ab, w_proj, b_proj, out);
}

// Round 3
// 1190.979 us; speedup vs baseline: 4.0143x; 4.0143x over previous
//
#include <hip/hip_runtime.h>

// Shapes: B=64, N=197, C=768, H=12, hd=64
// fp32 GEMMs done as split-bf16 (hi|lo concatenated on K -> K2=1536) MFMA.

#define NB   64
#define NN   197
#define NC   768
#define NH   12
#define HD   64
#define MM   (NB*NN)      // 12608
#define K2   1536         // 2*NC (hi|lo)
#define MR   12672        // 99*128 rows allocated (M padded to tile)

typedef __attribute__((ext_vector_type(8))) short short8;
typedef __attribute__((ext_vector_type(4))) float f32x4;
union U128 { uint4 u; short8 s; };

__device__ __forceinline__ unsigned bf16_rne(float f) {
    unsigned u = __float_as_uint(f);
    return (u + 0x7fffu + ((u >> 16) & 1u)) >> 16;
}
__device__ __forceinline__ unsigned pack2_bf16(float lo, float hi) {
    return bf16_rne(lo) | (bf16_rne(hi) << 16);
}

// async global->LDS, 16B/lane; LDS dest = wave-uniform base + lane*16
__device__ __forceinline__ void gld16(unsigned short* lds, const unsigned short* g) {
    __builtin_amdgcn_global_load_lds(
        (const __attribute__((address_space(1))) void*)g,
        (__attribute__((address_space(3))) void*)lds, 16, 0, 0);
}

// ---------------------------------------------------------------------------
// fp32 [rows x 768] -> bf16 hi|lo [rows x 1536]
// ---------------------------------------------------------------------------
__global__ __launch_bounds__(256) void convert_hilo(
    const float* __restrict__ src, unsigned short* __restrict__ dst, int nquads)
{
    int idx = blockIdx.x * 256 + threadIdx.x;
    if (idx >= nquads) return;
    int r = idx / 192;
    int c = (idx - r * 192) * 4;
    float4 f = *(const float4*)(src + (size_t)r * NC + c);
    unsigned h0 = bf16_rne(f.x), h1 = bf16_rne(f.y), h2 = bf16_rne(f.z), h3 = bf16_rne(f.w);
    float r0 = f.x - __uint_as_float(h0 << 16);
    float r1 = f.y - __uint_as_float(h1 << 16);
    float r2 = f.z - __uint_as_float(h2 << 16);
    float r3 = f.w - __uint_as_float(h3 << 16);
    ushort4 hv = { (unsigned short)h0, (unsigned short)h1, (unsigned short)h2, (unsigned short)h3 };
    ushort4 lv = { (unsigned short)bf16_rne(r0), (unsigned short)bf16_rne(r1),
                   (unsigned short)bf16_rne(r2), (unsigned short)bf16_rne(r3) };
    size_t base = (size_t)r * K2 + c;
    *(ushort4*)(dst + base) = hv;
    *(ushort4*)(dst + base + NC) = lv;
}

// ---------------------------------------------------------------------------
// bf16 MFMA mainloop: C[128,128] tile of A2[.,K2] * B2[.,K2]^T.
// LDS chunk-swizzle folded into per-lane GLOBAL addresses:
//   LDS[row][slot s] holds global 16B-chunk (s ^ (row&7)) of that row.
// Frag reads then hit slot (chunk ^ (row&7)) -> 2 lanes/bank (free).
// ---------------------------------------------------------------------------
__device__ __forceinline__ void gemm_mainloop(
    const unsigned short* __restrict__ A2, const unsigned short* __restrict__ B2,
    int m0, int n0, unsigned short* Abuf, unsigned short* Bbuf, f32x4 acc[4][4])
{
    const int tid = threadIdx.x;
    const int w = tid >> 6, lane = tid & 63;
    const int wm = w & 1, wn = w >> 1;
    const int lr = lane >> 3, lc = lane & 7;
    const int gch = lc ^ lr;                 // global chunk this lane fetches

    const unsigned short* Ag = A2 + (size_t)(m0 + w * 32 + lr) * K2 + gch * 8;
    const unsigned short* Bg = B2 + (size_t)(n0 + w * 32 + lr) * K2 + gch * 8;
    unsigned short* Al = Abuf + (w * 32) * 64;
    unsigned short* Bl = Bbuf + (w * 32) * 64;

    // frag read offsets (ushort idx) for k0=0; k0=1 (chunk+4) == idx ^ 32
    int aoff[4], boff[4];
    const int quad = lane >> 4, l15 = lane & 15;
    #pragma unroll
    for (int t = 0; t < 4; t++) {
        int ra = wm * 64 + t * 16 + l15;
        aoff[t] = ra * 64 + ((quad ^ (ra & 7)) << 3);
        int rb = wn * 64 + t * 16 + l15;
        boff[t] = rb * 64 + ((quad ^ (rb & 7)) << 3);
    }

    for (int ks = 0; ks < 24; ks++) {
        __syncthreads();                     // prev compute done before overwrite
        #pragma unroll
        for (int it = 0; it < 4; it++) {
            gld16(Al + it * 8 * 64, Ag + (size_t)it * 8 * K2);
            gld16(Bl + it * 8 * 64, Bg + (size_t)it * 8 * K2);
        }
        __syncthreads();                     // vmcnt drained -> LDS valid
        #pragma unroll
        for (int k0 = 0; k0 < 2; k0++) {
            U128 af[4], bf[4];
            #pragma unroll
            for (int t = 0; t < 4; t++) {
                af[t].u = *(const uint4*)&Abuf[aoff[t] ^ (k0 << 5)];
                bf[t].u = *(const uint4*)&Bbuf[boff[t] ^ (k0 << 5)];
            }
            #pragma unroll
            for (int i = 0; i < 4; i++)
                #pragma unroll
                for (int j = 0; j < 4; j++)
                    acc[i][j] = __builtin_amdgcn_mfma_f32_16x16x32_bf16(
                        af[i].s, bf[j].s, acc[i][j], 0, 0, 0);
        }
        Ag += 64; Bg += 64;
    }
}

// GEMM1: X2[MR,K2] * W2[2304,K2]^T -> scatter q/k/v [B,H,N,hd] fp32
__global__ __launch_bounds__(256) void gemm_qkv_mfma(
    const unsigned short* __restrict__ A2, const unsigned short* __restrict__ B2,
    float* __restrict__ qb, float* __restrict__ kb, float* __restrict__ vb)
{
    __shared__ unsigned short Abuf[128 * 64];
    __shared__ unsigned short Bbuf[128 * 64];
    f32x4 acc[4][4];
    f32x4 z = {0.f, 0.f, 0.f, 0.f};
    #pragma unroll
    for (int i = 0; i < 4; i++)
        #pragma unroll
        for (int j = 0; j < 4; j++) acc[i][j] = z;

    const int m0 = blockIdx.x * 128, n0 = blockIdx.y * 128;
    gemm_mainloop(A2, B2, m0, n0, Abuf, Bbuf, acc);

    const int tid = threadIdx.x;
    const int w = tid >> 6, lane = tid & 63;
    const int wm = w & 1, wn = w >> 1;
    const int quad = lane >> 4, l15 = lane & 15;
    #pragma unroll
    for (int nt = 0; nt < 4; nt++) {
        int nb = n0 + wn * 64 + nt * 16;     // 16-aligned -> single (tq,hh)
        int tq = nb / NC;
        int wi = nb - tq * NC;
        int hh = wi >> 6;
        int d0 = (wi & 63) + l15;
        float* dst = (tq == 0) ? qb : (tq == 1) ? kb : vb;
        float scale = (tq == 0) ? 0.125f : 1.0f;
        #pragma unroll
        for (int mt = 0; mt < 4; mt++) {
            #pragma unroll
            for (int r = 0; r < 4; r++) {
                int m = m0 + wm * 64 + mt * 16 + quad * 4 + r;
                if (m < MM) {
                    int b_ = m / NN, n_ = m - b_ * NN;
                    dst[(((size_t)b_ * NH + hh) * NN + n_) * HD + d0] = acc[mt][nt][r] * scale;
                }
            }
        }
    }
}

// GEMM2: AB2[MR,K2] * WP2[768,K2]^T + bias -> out [M,768] fp32
__global__ __launch_bounds__(256) void gemm_proj_mfma(
    const unsigned short* __restrict__ A2, const unsigned short* __restrict__ B2,
    const float* __restrict__ bias, float* __restrict__ out)
{
    __shared__ unsigned short Abuf[128 * 64];
    __shared__ unsigned short Bbuf[128 * 64];
    f32x4 acc[4][4];
    f32x4 z = {0.f, 0.f, 0.f, 0.f};
    #pragma unroll
    for (int i = 0; i < 4; i++)
        #pragma unroll
        for (int j = 0; j < 4; j++) acc[i][j] = z;

    const int m0 = blockIdx.x * 128, n0 = blockIdx.y * 128;
    gemm_mainloop(A2, B2, m0, n0, Abuf, Bbuf, acc);

    const int tid = threadIdx.x;
    const int w = tid >> 6, lane = tid & 63;
    const int wm = w & 1, wn = w >> 1;
    const int quad = lane >> 4, l15 = lane & 15;
    #pragma unroll
    for (int nt = 0; nt < 4; nt++) {
        int col = n0 + wn * 64 + nt * 16 + l15;
        float bi = bias[col];
        #pragma unroll
        for (int mt = 0; mt < 4; mt++) {
            #pragma unroll
            for (int r = 0; r < 4; r++) {
                int m = m0 + wm * 64 + mt * 16 + quad * 4 + r;
                if (m < MM)
                    out[(size_t)m * NC + col] = acc[mt][nt][r] + bi;
            }
        }
    }
}

// ---------------------------------------------------------------------------
// Attention: grid (768,4), 256 threads. K bf16 in LDS (XOR-swizzled), Q fp32
// via L1 broadcast, V fp32 coalesced from global. Output written as bf16
// hi|lo directly into ab2[MR,K2] for the proj MFMA GEMM.
// Plain launch_bounds: R2's (256,4) starved VGPRs (64) -> scratch spills.
// ---------------------------------------------------------------------------
__global__ __launch_bounds__(256) void attn_kernel(
    const float* __restrict__ qb, const float* __restrict__ kb,
    const float* __restrict__ vb, const float* __restrict__ table,
    const int* __restrict__ rel_index, unsigned short* __restrict__ ab2)
{
    __shared__ unsigned short Kbf[NN * HD];   // bf16; 16B chunk c at c^(m&7)
    __shared__ float Psh[4][4][200];

    const int bh = blockIdx.x;
    const int b = bh / NH, h = bh % NH;
    const int tid = threadIdx.x;
    const int w = tid >> 6, lane = tid & 63;
    const size_t base = (size_t)bh * (NN * HD);
    const float* kg = kb + base;
    const float* vg = vb + base;
    const float* qg = qb + base;

    for (int i = tid; i < NN * 8; i += 256) {
        int m = i >> 3, c = i & 7;
        const float* src = kg + m * HD + (c << 3);
        float4 f0 = *(const float4*)(src);
        float4 f1 = *(const float4*)(src + 4);
        uint4 u;
        u.x = pack2_bf16(f0.x, f0.y);
        u.y = pack2_bf16(f0.z, f0.w);
        u.z = pack2_bf16(f1.x, f1.y);
        u.w = pack2_bf16(f1.z, f1.w);
        *(uint4*)&Kbf[m * HD + ((c ^ (m & 7)) << 3)] = u;
    }
    __syncthreads();

    float* pw0 = Psh[w][0]; float* pw1 = Psh[w][1];
    float* pw2 = Psh[w][2]; float* pw3 = Psh[w][3];

    const int worker = blockIdx.y * 4 + w;    // 0..15

    for (int t = worker; t < 50; t += 16) {
        int nq[4];
        #pragma unroll
        for (int qi = 0; qi < 4; qi++) {
            int n = t * 4 + qi; nq[qi] = (n > 196) ? 196 : n;
        }

        float s[4][4];
        #pragma unroll
        for (int qi = 0; qi < 4; qi++) {
            const int* ri = rel_index + nq[qi] * NN;
            #pragma unroll
            for (int j = 0; j < 4; j++) {
                int m = lane + 64 * j;
                s[qi][j] = (m < NN) ? table[ri[m] * NH + h] : -1e30f;
            }
        }
        int mrow[4];
        #pragma unroll
        for (int j = 0; j < 4; j++) {
            int m = lane + 64 * j; mrow[j] = (m < NN) ? m : 196;
        }

        #pragma unroll
        for (int d8 = 0; d8 < 8; d8++) {
            float4 q0[4], q1[4];
            #pragma unroll
            for (int qi = 0; qi < 4; qi++) {
                const float* qp = qg + nq[qi] * HD + (d8 << 3);
                q0[qi] = *(const float4*)(qp);
                q1[qi] = *(const float4*)(qp + 4);
            }
            #pragma unroll
            for (int j = 0; j < 4; j++) {
                uint4 ku = *(const uint4*)&Kbf[mrow[j] * HD + ((d8 ^ (mrow[j] & 7)) << 3)];
                float k0 = __uint_as_float(ku.x << 16);
                float k1 = __uint_as_float(ku.x & 0xffff0000u);
                float k2 = __uint_as_float(ku.y << 16);
                float k3 = __uint_as_float(ku.y & 0xffff0000u);
                float k4 = __uint_as_float(ku.z << 16);
                float k5 = __uint_as_float(ku.z & 0xffff0000u);
                float k6 = __uint_as_float(ku.w << 16);
                float k7 = __uint_as_float(ku.w & 0xffff0000u);
                #pragma unroll
                for (int qi = 0; qi < 4; qi++) {
                    float acc = s[qi][j];
                    acc = fmaf(q0[qi].x, k0, acc);
                    acc = fmaf(q0[qi].y, k1, acc);
                    acc = fmaf(q0[qi].z, k2, acc);
                    acc = fmaf(q0[qi].w, k3, acc);
                    acc = fmaf(q1[qi].x, k4, acc);
                    acc = fmaf(q1[qi].y, k5, acc);
                    acc = fmaf(q1[qi].z, k6, acc);
                    acc = fmaf(q1[qi].w, k7, acc);
                    s[qi][j] = acc;
                }
            }
        }

        #pragma unroll
        for (int qi = 0; qi < 4; qi++) {
            float mx = fmaxf(fmaxf(s[qi][0], s[qi][1]), fmaxf(s[qi][2], s[qi][3]));
            #pragma unroll
            for (int off = 32; off > 0; off >>= 1)
                mx = fmaxf(mx, __shfl_xor(mx, off));
            float e[4];
            e[0] = __expf(s[qi][0] - mx); e[1] = __expf(s[qi][1] - mx);
            e[2] = __expf(s[qi][2] - mx); e[3] = __expf(s[qi][3] - mx);
            float sum = (e[0] + e[1]) + (e[2] + e[3]);
            #pragma unroll
            for (int off = 32; off > 0; off >>= 1)
                sum += __shfl_xor(sum, off);
            float inv = 1.0f / sum;
            float* pw = Psh[w][qi];
            #pragma unroll
            for (int j = 0; j < 4; j++) {
                int m = lane + 64 * j;
                if (m < 200) pw[m] = e[j] * inv;
            }
        }

        float o[4] = {0.f, 0.f, 0.f, 0.f};
        #pragma unroll 2
        for (int s4 = 0; s4 < 49; s4++) {
            const int mb = s4 * 4;
            float4 P0 = *(const float4*)&pw0[mb];
            float4 P1 = *(const float4*)&pw1[mb];
            float4 P2 = *(const float4*)&pw2[mb];
            float4 P3 = *(const float4*)&pw3[mb];
            const float* vp = vg + mb * HD + lane;
            float v0 = vp[0], v1 = vp[64], v2 = vp[128], v3 = vp[192];
            o[0] = fmaf(P0.x, v0, fmaf(P0.y, v1, fmaf(P0.z, v2, fmaf(P0.w, v3, o[0]))));
            o[1] = fmaf(P1.x, v0, fmaf(P1.y, v1, fmaf(P1.z, v2, fmaf(P1.w, v3, o[1]))));
            o[2] = fmaf(P2.x, v0, fmaf(P2.y, v1, fmaf(P2.z, v2, fmaf(P2.w, v3, o[2]))));
            o[3] = fmaf(P3.x, v0, fmaf(P3.y, v1, fmaf(P3.z, v2, fmaf(P3.w, v3, o[3]))));
        }
        {
            float v0 = vg[196 * HD + lane];
            o[0] = fmaf(pw0[196], v0, o[0]);
            o[1] = fmaf(pw1[196], v0, o[1]);
            o[2] = fmaf(pw2[196], v0, o[2]);
            o[3] = fmaf(pw3[196], v0, o[3]);
        }

        // write hi|lo bf16 into ab2 for the proj MFMA GEMM
        #pragma unroll
        for (int qi = 0; qi < 4; qi++) {
            int n = t * 4 + qi;
            if (n < NN) {
                float v = o[qi];
                unsigned hi = bf16_rne(v);
                float hif = __uint_as_float(hi << 16);
                unsigned lo = bf16_rne(v - hif);
                size_t rb = ((size_t)b * NN + n) * K2 + h * HD + lane;
                ab2[rb] = (unsigned short)hi;
                ab2[rb + NC] = (unsigned short)lo;
            }
        }
    }
}

// ---------------------------------------------------------------------------
extern "C" void kernel_launch(void* const* d_in, const int* in_sizes, int n_in,
                              void* d_out, int out_size, void* d_ws, size_t ws_size,
                              hipStream_t stream)
{
    const float* x        = (const float*)d_in[0];
    const float* table    = (const float*)d_in[1];
    const float* w_qkv    = (const float*)d_in[2];
    const float* w_proj   = (const float*)d_in[3];
    const float* b_proj   = (const float*)d_in[4];
    const int*   rel_idx  = (const int*)d_in[5];
    float* out = (float*)d_out;

    unsigned short* x2  = (unsigned short*)d_ws;            // MR*K2
    unsigned short* w2  = x2 + (size_t)MR * K2;             // 2304*K2
    unsigned short* wp2 = w2 + (size_t)2304 * K2;           // 768*K2
    unsigned short* ab2 = wp2 + (size_t)768 * K2;           // MR*K2
    float* qb = (float*)(ab2 + (size_t)MR * K2);
    float* kb = qb + (size_t)NB * NH * NN * HD;
    float* vb = kb + (size_t)NB * NH * NN * HD;

    // fp32 -> bf16 hi|lo
    convert_hilo<<<(MM * 192 + 255) / 256, 256, 0, stream>>>(x, x2, MM * 192);
    convert_hilo<<<(2304 * 192 + 255) / 256, 256, 0, stream>>>(w_qkv, w2, 2304 * 192);
    convert_hilo<<<(768 * 192 + 255) / 256, 256, 0, stream>>>(w_proj, wp2, 768 * 192);

    gemm_qkv_mfma<<<dim3(99, 18), 256, 0, stream>>>(x2, w2, qb, kb, vb);
    attn_kernel<<<dim3(NB * NH, 4), 256, 0, stream>>>(qb, kb, vb, table, rel_idx, ab2);
    gemm_proj_mfma<<<dim3(99, 6), 256, 0, stream>>>(ab2, wp2, b_proj, out);
}

// Round 4
// 410.327 us; speedup vs baseline: 11.6516x; 2.9025x over previous
//
#include <hip/hip_runtime.h>

// Shapes: B=64, N=197, C=768, H=12, hd=64
// GEMMs: split-bf16 (hi|lo on K -> K2=1536) MFMA. Attention: MFMA flash-lite.

#define NB   64
#define NN   197
#define NC   768
#define NH   12
#define HD   64
#define MM   (NB*NN)      // 12608
#define K2   1536
#define MR   12672        // 99*128
#define NP   208          // N padded to 13*16
#define SZQ  ((size_t)NB * NH * NN * HD)   // 9,682,944 elems per q/k/v array

typedef unsigned short ushort_t;
typedef __attribute__((ext_vector_type(8))) short short8;
typedef __attribute__((ext_vector_type(4))) float f32x4;
union U128 { uint4 u; short8 s; };

__device__ __forceinline__ unsigned bf16_rne(float f) {
    unsigned u = __float_as_uint(f);
    return (u + 0x7fffu + ((u >> 16) & 1u)) >> 16;
}

__device__ __forceinline__ void gld16(unsigned short* lds, const unsigned short* g) {
    __builtin_amdgcn_global_load_lds(
        (const __attribute__((address_space(1))) void*)g,
        (__attribute__((address_space(3))) void*)lds, 16, 0, 0);
}

// ---------------------------------------------------------------------------
// fp32 [rows x 768] -> bf16 hi|lo [rows x 1536]
// ---------------------------------------------------------------------------
__global__ __launch_bounds__(256) void convert_hilo(
    const float* __restrict__ src, ushort_t* __restrict__ dst, int nquads)
{
    int idx = blockIdx.x * 256 + threadIdx.x;
    if (idx >= nquads) return;
    int r = idx / 192;
    int c = (idx - r * 192) * 4;
    float4 f = *(const float4*)(src + (size_t)r * NC + c);
    unsigned h0 = bf16_rne(f.x), h1 = bf16_rne(f.y), h2 = bf16_rne(f.z), h3 = bf16_rne(f.w);
    float r0 = f.x - __uint_as_float(h0 << 16);
    float r1 = f.y - __uint_as_float(h1 << 16);
    float r2 = f.z - __uint_as_float(h2 << 16);
    float r3 = f.w - __uint_as_float(h3 << 16);
    ushort4 hv = { (ushort_t)h0, (ushort_t)h1, (ushort_t)h2, (ushort_t)h3 };
    ushort4 lv = { (ushort_t)bf16_rne(r0), (ushort_t)bf16_rne(r1),
                   (ushort_t)bf16_rne(r2), (ushort_t)bf16_rne(r3) };
    size_t base = (size_t)r * K2 + c;
    *(ushort4*)(dst + base) = hv;
    *(ushort4*)(dst + base + NC) = lv;
}

// ---------------------------------------------------------------------------
// biasM[h][n][m] = table[rel_index[n,m]][h], -1e30 outside valid range
// ---------------------------------------------------------------------------
__global__ __launch_bounds__(256) void bias_precompute(
    const float* __restrict__ table, const int* __restrict__ rel_index,
    float* __restrict__ biasM)
{
    int i = blockIdx.x * 256 + threadIdx.x;
    if (i >= NH * NP * NP) return;
    int h = i / (NP * NP);
    int rem = i - h * NP * NP;
    int n = rem / NP, m = rem - (rem / NP) * NP;
    float v = -1e30f;
    if (n < NN && m < NN) v = table[rel_index[n * NN + m] * NH + h];
    biasM[i] = v;
}

// ---------------------------------------------------------------------------
// bf16 MFMA mainloop (unchanged from R3, verified).
// ---------------------------------------------------------------------------
__device__ __forceinline__ void gemm_mainloop(
    const ushort_t* __restrict__ A2, const ushort_t* __restrict__ B2,
    int m0, int n0, ushort_t* Abuf, ushort_t* Bbuf, f32x4 acc[4][4])
{
    const int tid = threadIdx.x;
    const int w = tid >> 6, lane = tid & 63;
    const int wm = w & 1, wn = w >> 1;
    const int lr = lane >> 3, lc = lane & 7;
    const int gch = lc ^ lr;

    const ushort_t* Ag = A2 + (size_t)(m0 + w * 32 + lr) * K2 + gch * 8;
    const ushort_t* Bg = B2 + (size_t)(n0 + w * 32 + lr) * K2 + gch * 8;
    ushort_t* Al = Abuf + (w * 32) * 64;
    ushort_t* Bl = Bbuf + (w * 32) * 64;

    int aoff[4], boff[4];
    const int quad = lane >> 4, l15 = lane & 15;
    #pragma unroll
    for (int t = 0; t < 4; t++) {
        int ra = wm * 64 + t * 16 + l15;
        aoff[t] = ra * 64 + ((quad ^ (ra & 7)) << 3);
        int rb = wn * 64 + t * 16 + l15;
        boff[t] = rb * 64 + ((quad ^ (rb & 7)) << 3);
    }

    for (int ks = 0; ks < 24; ks++) {
        __syncthreads();
        #pragma unroll
        for (int it = 0; it < 4; it++) {
            gld16(Al + it * 8 * 64, Ag + (size_t)it * 8 * K2);
            gld16(Bl + it * 8 * 64, Bg + (size_t)it * 8 * K2);
        }
        __syncthreads();
        #pragma unroll
        for (int k0 = 0; k0 < 2; k0++) {
            U128 af[4], bf[4];
            #pragma unroll
            for (int t = 0; t < 4; t++) {
                af[t].u = *(const uint4*)&Abuf[aoff[t] ^ (k0 << 5)];
                bf[t].u = *(const uint4*)&Bbuf[boff[t] ^ (k0 << 5)];
            }
            #pragma unroll
            for (int i = 0; i < 4; i++)
                #pragma unroll
                for (int j = 0; j < 4; j++)
                    acc[i][j] = __builtin_amdgcn_mfma_f32_16x16x32_bf16(
                        af[i].s, bf[j].s, acc[i][j], 0, 0, 0);
        }
        Ag += 64; Bg += 64;
    }
}

// GEMM1: X2*W2^T -> qhi/qlo (scale folded), kbf, vbf  (all bf16 [bh][n][d])
__global__ __launch_bounds__(256) void gemm_qkv_mfma(
    const ushort_t* __restrict__ A2, const ushort_t* __restrict__ B2,
    ushort_t* __restrict__ qhi, ushort_t* __restrict__ qlo,
    ushort_t* __restrict__ kbf, ushort_t* __restrict__ vbf)
{
    __shared__ ushort_t Abuf[128 * 64];
    __shared__ ushort_t Bbuf[128 * 64];
    f32x4 acc[4][4];
    f32x4 z = {0.f, 0.f, 0.f, 0.f};
    #pragma unroll
    for (int i = 0; i < 4; i++)
        #pragma unroll
        for (int j = 0; j < 4; j++) acc[i][j] = z;

    const int m0 = blockIdx.x * 128, n0 = blockIdx.y * 128;
    gemm_mainloop(A2, B2, m0, n0, Abuf, Bbuf, acc);

    const int tid = threadIdx.x;
    const int w = tid >> 6, lane = tid & 63;
    const int wm = w & 1, wn = w >> 1;
    const int quad = lane >> 4, l15 = lane & 15;
    #pragma unroll
    for (int nt = 0; nt < 4; nt++) {
        int c0 = n0 + wn * 64 + nt * 16;
        int tq = c0 / NC;
        int wi = c0 - tq * NC;
        int hh = wi >> 6;
        int d0 = (wi & 63) + l15;
        #pragma unroll
        for (int mt = 0; mt < 4; mt++) {
            #pragma unroll
            for (int r = 0; r < 4; r++) {
                int m = m0 + wm * 64 + mt * 16 + quad * 4 + r;
                if (m < MM) {
                    int b_ = m / NN, n_ = m - b_ * NN;
                    size_t off = ((size_t)(b_ * NH + hh) * NN + n_) * HD + d0;
                    float v = acc[mt][nt][r];
                    if (tq == 0) {
                        v *= 0.125f;
                        unsigned hi = bf16_rne(v);
                        qhi[off] = (ushort_t)hi;
                        qlo[off] = (ushort_t)bf16_rne(v - __uint_as_float(hi << 16));
                    } else if (tq == 1) {
                        kbf[off] = (ushort_t)bf16_rne(v);
                    } else {
                        vbf[off] = (ushort_t)bf16_rne(v);
                    }
                }
            }
        }
    }
}

// GEMM2: AB2 * WP2^T + bias -> out fp32 (unchanged from R3)
__global__ __launch_bounds__(256) void gemm_proj_mfma(
    const ushort_t* __restrict__ A2, const ushort_t* __restrict__ B2,
    const float* __restrict__ bias, float* __restrict__ out)
{
    __shared__ ushort_t Abuf[128 * 64];
    __shared__ ushort_t Bbuf[128 * 64];
    f32x4 acc[4][4];
    f32x4 z = {0.f, 0.f, 0.f, 0.f};
    #pragma unroll
    for (int i = 0; i < 4; i++)
        #pragma unroll
        for (int j = 0; j < 4; j++) acc[i][j] = z;

    const int m0 = blockIdx.x * 128, n0 = blockIdx.y * 128;
    gemm_mainloop(A2, B2, m0, n0, Abuf, Bbuf, acc);

    const int tid = threadIdx.x;
    const int w = tid >> 6, lane = tid & 63;
    const int wm = w & 1, wn = w >> 1;
    const int quad = lane >> 4, l15 = lane & 15;
    #pragma unroll
    for (int nt = 0; nt < 4; nt++) {
        int col = n0 + wn * 64 + nt * 16 + l15;
        float bi = bias[col];
        #pragma unroll
        for (int mt = 0; mt < 4; mt++) {
            #pragma unroll
            for (int r = 0; r < 4; r++) {
                int m = m0 + wm * 64 + mt * 16 + quad * 4 + r;
                if (m < MM)
                    out[(size_t)m * NC + col] = acc[mt][nt][r] + bi;
            }
        }
    }
}

// ---------------------------------------------------------------------------
// MFMA attention. grid (768, 2) x 256 threads (4 waves).
// Per wave: 16-row Q-tile. S[13] tiles in regs (52 MFMAs: Qhi/Qlo x K),
// softmax via quad-group shfl, P -> LDS bf16 (stride 232, even bank spread),
// PV: 28 MFMAs with LDS-transposed Vt. Output bf16 hi/lo into ab2.
// ---------------------------------------------------------------------------
__global__ __launch_bounds__(256) void attn_mfma(
    const ushort_t* __restrict__ qhi, const ushort_t* __restrict__ qlo,
    const ushort_t* __restrict__ kbf, const ushort_t* __restrict__ vbf,
    const float* __restrict__ biasM, ushort_t* __restrict__ ab2)
{
    __shared__ ushort_t Vt[64 * 232];        // Vt[d][key], 29696 B
    __shared__ ushort_t Pl[4][16 * 232];     // per-wave P[q][key], 29696 B

    const int bh = blockIdx.x;
    const int b = bh / NH, h = bh % NH;
    const int tid = threadIdx.x;
    const int w = tid >> 6, lane = tid & 63;
    const int quad = lane >> 4, l15 = lane & 15;
    const size_t base = (size_t)bh * (NN * HD);
    const ushort_t* kg = kbf + base;
    const ushort_t* vg = vbf + base;
    const ushort_t* qhg = qhi + base;
    const ushort_t* qlg = qlo + base;

    // stage Vt (transpose): task = kc*64 + d; keys >= 197 -> 0
    for (int task = tid; task < 29 * 64; task += 256) {
        int kc = task >> 6, d = task & 63;
        ushort_t tmp[8];
        #pragma unroll
        for (int j = 0; j < 8; j++) {
            int key = kc * 8 + j;
            tmp[j] = (key < NN) ? vg[key * HD + d] : (ushort_t)0;
        }
        uint4 u;
        u.x = (unsigned)tmp[0] | ((unsigned)tmp[1] << 16);
        u.y = (unsigned)tmp[2] | ((unsigned)tmp[3] << 16);
        u.z = (unsigned)tmp[4] | ((unsigned)tmp[5] << 16);
        u.w = (unsigned)tmp[6] | ((unsigned)tmp[7] << 16);
        *(uint4*)&Vt[d * 232 + kc * 8] = u;
    }
    __syncthreads();

    const int worker = blockIdx.y * 4 + w;   // 0..7

    #pragma unroll
    for (int rep = 0; rep < 2; rep++) {
        int qt = worker + rep * 8;
        if (qt > 12) break;
        const int q0 = qt * 16;

        // Q fragments (hi/lo), row clamped
        int qrow = q0 + l15; if (qrow > NN - 1) qrow = NN - 1;
        U128 qh0, qh1, ql0, ql1;
        qh0.u = *(const uint4*)(qhg + (size_t)qrow * HD + quad * 8);
        qh1.u = *(const uint4*)(qhg + (size_t)qrow * HD + 32 + quad * 8);
        ql0.u = *(const uint4*)(qlg + (size_t)qrow * HD + quad * 8);
        ql1.u = *(const uint4*)(qlg + (size_t)qrow * HD + 32 + quad * 8);

        // S init from biasM (C-layout)
        f32x4 S[13];
        #pragma unroll
        for (int kt = 0; kt < 13; kt++) {
            #pragma unroll
            for (int r = 0; r < 4; r++)
                S[kt][r] = biasM[((size_t)h * NP + (q0 + quad * 4 + r)) * NP + kt * 16 + l15];
        }

        // QK^T
        #pragma unroll
        for (int kt = 0; kt < 13; kt++) {
            int krow = kt * 16 + l15; if (krow > NN - 1) krow = NN - 1;
            U128 k0, k1;
            k0.u = *(const uint4*)(kg + (size_t)krow * HD + quad * 8);
            k1.u = *(const uint4*)(kg + (size_t)krow * HD + 32 + quad * 8);
            S[kt] = __builtin_amdgcn_mfma_f32_16x16x32_bf16(qh0.s, k0.s, S[kt], 0, 0, 0);
            S[kt] = __builtin_amdgcn_mfma_f32_16x16x32_bf16(qh1.s, k1.s, S[kt], 0, 0, 0);
            S[kt] = __builtin_amdgcn_mfma_f32_16x16x32_bf16(ql0.s, k0.s, S[kt], 0, 0, 0);
            S[kt] = __builtin_amdgcn_mfma_f32_16x16x32_bf16(ql1.s, k1.s, S[kt], 0, 0, 0);
        }

        // softmax rows (row = quad*4+r, spread across 16 lanes l15)
        ushort_t* P = Pl[w];
        #pragma unroll
        for (int r = 0; r < 4; r++) {
            float mx = S[0][r];
            #pragma unroll
            for (int kt = 1; kt < 13; kt++) mx = fmaxf(mx, S[kt][r]);
            mx = fmaxf(mx, __shfl_xor(mx, 1));
            mx = fmaxf(mx, __shfl_xor(mx, 2));
            mx = fmaxf(mx, __shfl_xor(mx, 4));
            mx = fmaxf(mx, __shfl_xor(mx, 8));
            float sum = 0.f;
            #pragma unroll
            for (int kt = 0; kt < 13; kt++) {
                float e = __expf(S[kt][r] - mx);
                S[kt][r] = e;
                sum += e;
            }
            sum += __shfl_xor(sum, 1);
            sum += __shfl_xor(sum, 2);
            sum += __shfl_xor(sum, 4);
            sum += __shfl_xor(sum, 8);
            float inv = 1.0f / sum;
            int prow = quad * 4 + r;
            #pragma unroll
            for (int kt = 0; kt < 13; kt++)
                P[prow * 232 + kt * 16 + l15] = (ushort_t)bf16_rne(S[kt][r] * inv);
        }
        // zero P keys 208..231 (16 rows x 12 dwords = 192 = 3*64)
        #pragma unroll
        for (int z = 0; z < 3; z++) {
            int idx = z * 64 + lane;
            int row = idx / 12, c = idx - row * 12;
            *(unsigned*)&P[row * 232 + NP + 2 * c] = 0u;
        }

        // PV
        f32x4 O[4];
        f32x4 z4 = {0.f, 0.f, 0.f, 0.f};
        #pragma unroll
        for (int dt = 0; dt < 4; dt++) O[dt] = z4;
        #pragma unroll
        for (int ks = 0; ks < 7; ks++) {
            U128 pf;
            pf.u = *(const uint4*)&P[l15 * 232 + ks * 32 + quad * 8];
            #pragma unroll
            for (int dt = 0; dt < 4; dt++) {
                U128 vf;
                vf.u = *(const uint4*)&Vt[(dt * 16 + l15) * 232 + ks * 32 + quad * 8];
                O[dt] = __builtin_amdgcn_mfma_f32_16x16x32_bf16(pf.s, vf.s, O[dt], 0, 0, 0);
            }
        }

        // write O as bf16 hi/lo into ab2[(b*197+q)*1536 + h*64 + d]
        #pragma unroll
        for (int dt = 0; dt < 4; dt++) {
            #pragma unroll
            for (int r = 0; r < 4; r++) {
                int q = q0 + quad * 4 + r;
                if (q < NN) {
                    float v = O[dt][r];
                    unsigned hi = bf16_rne(v);
                    unsigned lo = bf16_rne(v - __uint_as_float(hi << 16));
                    size_t off = ((size_t)b * NN + q) * K2 + h * HD + dt * 16 + l15;
                    ab2[off] = (ushort_t)hi;
                    ab2[off + NC] = (ushort_t)lo;
                }
            }
        }
    }
}

// ---------------------------------------------------------------------------
extern "C" void kernel_launch(void* const* d_in, const int* in_sizes, int n_in,
                              void* d_out, int out_size, void* d_ws, size_t ws_size,
                              hipStream_t stream)
{
    const float* x        = (const float*)d_in[0];
    const float* table    = (const float*)d_in[1];
    const float* w_qkv    = (const float*)d_in[2];
    const float* w_proj   = (const float*)d_in[3];
    const float* b_proj   = (const float*)d_in[4];
    const int*   rel_idx  = (const int*)d_in[5];
    float* out = (float*)d_out;

    ushort_t* x2  = (ushort_t*)d_ws;                        // MR*K2
    ushort_t* w2  = x2 + (size_t)MR * K2;                   // 2304*K2
    ushort_t* wp2 = w2 + (size_t)2304 * K2;                 // 768*K2
    ushort_t* ab2 = wp2 + (size_t)768 * K2;                 // MR*K2
    ushort_t* qhi = ab2 + (size_t)MR * K2;                  // SZQ each
    ushort_t* qlo = qhi + SZQ;
    ushort_t* kbf = qlo + SZQ;
    ushort_t* vbf = kbf + SZQ;
    float* biasM  = (float*)(vbf + SZQ);                    // 12*208*208

    convert_hilo<<<(MM * 192 + 255) / 256, 256, 0, stream>>>(x, x2, MM * 192);
    convert_hilo<<<(2304 * 192 + 255) / 256, 256, 0, stream>>>(w_qkv, w2, 2304 * 192);
    convert_hilo<<<(768 * 192 + 255) / 256, 256, 0, stream>>>(w_proj, wp2, 768 * 192);
    bias_precompute<<<(NH * NP * NP + 255) / 256, 256, 0, stream>>>(table, rel_idx, biasM);

    gemm_qkv_mfma<<<dim3(99, 18), 256, 0, stream>>>(x2, w2, qhi, qlo, kbf, vbf);
    attn_mfma<<<dim3(NB * NH, 2), 256, 0, stream>>>(qhi, qlo, kbf, vbf, biasM, ab2);
    gemm_proj_mfma<<<dim3(99, 6), 256, 0, stream>>>(ab2, wp2, b_proj, out);
}

// Round 5
// 354.400 us; speedup vs baseline: 13.4903x; 1.1578x over previous
//
#include <hip/hip_runtime.h>

// Shapes: B=64, N=197, C=768, H=12, hd=64
// GEMMs: split-bf16 MFMA. Q path exact (hi|lo, K2=1536); K/V plain bf16 (K=768).
// Attention: MFMA flash-lite with precomputed bias matrix.

#define NB   64
#define NN   197
#define NC   768
#define NH   12
#define HD   64
#define MM   (NB*NN)      // 12608
#define K2   1536
#define MR   12672        // 99*128
#define NP   208          // N padded to 13*16
#define SZQ  ((size_t)NB * NH * NN * HD)

typedef unsigned short ushort_t;
typedef __attribute__((ext_vector_type(8))) short short8;
typedef __attribute__((ext_vector_type(4))) float f32x4;
union U128 { uint4 u; short8 s; };

__device__ __forceinline__ unsigned bf16_rne(float f) {
    unsigned u = __float_as_uint(f);
    return (u + 0x7fffu + ((u >> 16) & 1u)) >> 16;
}

__device__ __forceinline__ void gld16(unsigned short* lds, const unsigned short* g) {
    __builtin_amdgcn_global_load_lds(
        (const __attribute__((address_space(1))) void*)g,
        (__attribute__((address_space(3))) void*)lds, 16, 0, 0);
}

// ---------------------------------------------------------------------------
// Fused fp32 -> bf16 hi|lo for x, w_qkv, w_proj (one launch)
// ---------------------------------------------------------------------------
__global__ __launch_bounds__(256) void convert_all(
    const float* __restrict__ x, const float* __restrict__ w_qkv,
    const float* __restrict__ w_proj,
    ushort_t* __restrict__ x2, ushort_t* __restrict__ w2,
    ushort_t* __restrict__ wp2)
{
    int idx = blockIdx.x * 256 + threadIdx.x;
    if (idx >= (MM + 2304 + 768) * 192) return;
    int r = idx / 192;
    int c = (idx - r * 192) * 4;
    const float* src;
    ushort_t* dst;
    if (r < MM)               { src = x + (size_t)r * NC;                dst = x2 + (size_t)r * K2; }
    else if (r < MM + 2304)   { int rr = r - MM;   src = w_qkv + (size_t)rr * NC;  dst = w2 + (size_t)rr * K2; }
    else                      { int rr = r - MM - 2304; src = w_proj + (size_t)rr * NC; dst = wp2 + (size_t)rr * K2; }
    float4 f = *(const float4*)(src + c);
    unsigned h0 = bf16_rne(f.x), h1 = bf16_rne(f.y), h2 = bf16_rne(f.z), h3 = bf16_rne(f.w);
    float r0 = f.x - __uint_as_float(h0 << 16);
    float r1 = f.y - __uint_as_float(h1 << 16);
    float r2 = f.z - __uint_as_float(h2 << 16);
    float r3 = f.w - __uint_as_float(h3 << 16);
    ushort4 hv = { (ushort_t)h0, (ushort_t)h1, (ushort_t)h2, (ushort_t)h3 };
    ushort4 lv = { (ushort_t)bf16_rne(r0), (ushort_t)bf16_rne(r1),
                   (ushort_t)bf16_rne(r2), (ushort_t)bf16_rne(r3) };
    *(ushort4*)(dst + c) = hv;
    *(ushort4*)(dst + c + NC) = lv;
}

// ---------------------------------------------------------------------------
// biasM[h][n][m] = table[rel_index[n,m]][h], -1e30 outside valid range
// ---------------------------------------------------------------------------
__global__ __launch_bounds__(256) void bias_precompute(
    const float* __restrict__ table, const int* __restrict__ rel_index,
    float* __restrict__ biasM)
{
    int i = blockIdx.x * 256 + threadIdx.x;
    if (i >= NH * NP * NP) return;
    int h = i / (NP * NP);
    int rem = i - h * NP * NP;
    int n = rem / NP, m = rem - (rem / NP) * NP;
    float v = -1e30f;
    if (n < NN && m < NN) v = table[rel_index[n * NN + m] * NH + h];
    biasM[i] = v;
}

// ---------------------------------------------------------------------------
// bf16 MFMA mainloop; kiters selects K depth (24 = hi|lo exact, 12 = hi only).
// ---------------------------------------------------------------------------
__device__ __forceinline__ void gemm_mainloop(
    const ushort_t* __restrict__ A2, const ushort_t* __restrict__ B2,
    int m0, int n0, int kiters, ushort_t* Abuf, ushort_t* Bbuf, f32x4 acc[4][4])
{
    const int tid = threadIdx.x;
    const int w = tid >> 6, lane = tid & 63;
    const int wm = w & 1, wn = w >> 1;
    const int lr = lane >> 3, lc = lane & 7;
    const int gch = lc ^ lr;

    const ushort_t* Ag = A2 + (size_t)(m0 + w * 32 + lr) * K2 + gch * 8;
    const ushort_t* Bg = B2 + (size_t)(n0 + w * 32 + lr) * K2 + gch * 8;
    ushort_t* Al = Abuf + (w * 32) * 64;
    ushort_t* Bl = Bbuf + (w * 32) * 64;

    int aoff[4], boff[4];
    const int quad = lane >> 4, l15 = lane & 15;
    #pragma unroll
    for (int t = 0; t < 4; t++) {
        int ra = wm * 64 + t * 16 + l15;
        aoff[t] = ra * 64 + ((quad ^ (ra & 7)) << 3);
        int rb = wn * 64 + t * 16 + l15;
        boff[t] = rb * 64 + ((quad ^ (rb & 7)) << 3);
    }

    for (int ks = 0; ks < kiters; ks++) {
        __syncthreads();
        #pragma unroll
        for (int it = 0; it < 4; it++) {
            gld16(Al + it * 8 * 64, Ag + (size_t)it * 8 * K2);
            gld16(Bl + it * 8 * 64, Bg + (size_t)it * 8 * K2);
        }
        __syncthreads();
        #pragma unroll
        for (int k0 = 0; k0 < 2; k0++) {
            U128 af[4], bf[4];
            #pragma unroll
            for (int t = 0; t < 4; t++) {
                af[t].u = *(const uint4*)&Abuf[aoff[t] ^ (k0 << 5)];
                bf[t].u = *(const uint4*)&Bbuf[boff[t] ^ (k0 << 5)];
            }
            #pragma unroll
            for (int i = 0; i < 4; i++)
                #pragma unroll
                for (int j = 0; j < 4; j++)
                    acc[i][j] = __builtin_amdgcn_mfma_f32_16x16x32_bf16(
                        af[i].s, bf[j].s, acc[i][j], 0, 0, 0);
        }
        Ag += 64; Bg += 64;
    }
}

// GEMM1: X2*W2^T -> qhi/qlo (scale folded, exact K2), kbf/vbf (plain bf16 K=768)
__global__ __launch_bounds__(256) void gemm_qkv_mfma(
    const ushort_t* __restrict__ A2, const ushort_t* __restrict__ B2,
    ushort_t* __restrict__ qhi, ushort_t* __restrict__ qlo,
    ushort_t* __restrict__ kbf, ushort_t* __restrict__ vbf)
{
    __shared__ ushort_t Abuf[128 * 64];
    __shared__ ushort_t Bbuf[128 * 64];
    f32x4 acc[4][4];
    f32x4 z = {0.f, 0.f, 0.f, 0.f};
    #pragma unroll
    for (int i = 0; i < 4; i++)
        #pragma unroll
        for (int j = 0; j < 4; j++) acc[i][j] = z;

    const int m0 = blockIdx.x * 128, n0 = blockIdx.y * 128;
    const int kiters = (n0 < NC) ? 24 : 12;   // Q exact; K,V hi-only
    gemm_mainloop(A2, B2, m0, n0, kiters, Abuf, Bbuf, acc);

    const int tid = threadIdx.x;
    const int w = tid >> 6, lane = tid & 63;
    const int wm = w & 1, wn = w >> 1;
    const int quad = lane >> 4, l15 = lane & 15;
    #pragma unroll
    for (int nt = 0; nt < 4; nt++) {
        int c0 = n0 + wn * 64 + nt * 16;
        int tq = c0 / NC;
        int wi = c0 - tq * NC;
        int hh = wi >> 6;
        int d0 = (wi & 63) + l15;
        #pragma unroll
        for (int mt = 0; mt < 4; mt++) {
            #pragma unroll
            for (int r = 0; r < 4; r++) {
                int m = m0 + wm * 64 + mt * 16 + quad * 4 + r;
                if (m < MM) {
                    int b_ = m / NN, n_ = m - b_ * NN;
                    size_t off = ((size_t)(b_ * NH + hh) * NN + n_) * HD + d0;
                    float v = acc[mt][nt][r];
                    if (tq == 0) {
                        v *= 0.125f;
                        unsigned hi = bf16_rne(v);
                        qhi[off] = (ushort_t)hi;
                        qlo[off] = (ushort_t)bf16_rne(v - __uint_as_float(hi << 16));
                    } else if (tq == 1) {
                        kbf[off] = (ushort_t)bf16_rne(v);
                    } else {
                        vbf[off] = (ushort_t)bf16_rne(v);
                    }
                }
            }
        }
    }
}

// GEMM2: AB2 * WP2^T + bias -> out fp32 (exact K2)
__global__ __launch_bounds__(256) void gemm_proj_mfma(
    const ushort_t* __restrict__ A2, const ushort_t* __restrict__ B2,
    const float* __restrict__ bias, float* __restrict__ out)
{
    __shared__ ushort_t Abuf[128 * 64];
    __shared__ ushort_t Bbuf[128 * 64];
    f32x4 acc[4][4];
    f32x4 z = {0.f, 0.f, 0.f, 0.f};
    #pragma unroll
    for (int i = 0; i < 4; i++)
        #pragma unroll
        for (int j = 0; j < 4; j++) acc[i][j] = z;

    const int m0 = blockIdx.x * 128, n0 = blockIdx.y * 128;
    gemm_mainloop(A2, B2, m0, n0, 24, Abuf, Bbuf, acc);

    const int tid = threadIdx.x;
    const int w = tid >> 6, lane = tid & 63;
    const int wm = w & 1, wn = w >> 1;
    const int quad = lane >> 4, l15 = lane & 15;
    #pragma unroll
    for (int nt = 0; nt < 4; nt++) {
        int col = n0 + wn * 64 + nt * 16 + l15;
        float bi = bias[col];
        #pragma unroll
        for (int mt = 0; mt < 4; mt++) {
            #pragma unroll
            for (int r = 0; r < 4; r++) {
                int m = m0 + wm * 64 + mt * 16 + quad * 4 + r;
                if (m < MM)
                    out[(size_t)m * NC + col] = acc[mt][nt][r] + bi;
            }
        }
    }
}

// ---------------------------------------------------------------------------
// MFMA attention. grid (768, 2) x 256 threads (4 waves).
// V staged coalesced into Pl region (not yet live), transposed LDS->LDS into
// Vt (conflict-free). Per wave: 16-row Q-tile, S[13] in regs (52 MFMAs),
// quad-shfl softmax, P->LDS bf16, PV 28 MFMAs. Output bf16 hi/lo into ab2.
// ---------------------------------------------------------------------------
__global__ __launch_bounds__(256) void attn_mfma(
    const ushort_t* __restrict__ qhi, const ushort_t* __restrict__ qlo,
    const ushort_t* __restrict__ kbf, const ushort_t* __restrict__ vbf,
    const float* __restrict__ biasM, ushort_t* __restrict__ ab2)
{
    __shared__ ushort_t Vt[64 * 232];        // Vt[d][key], 29696 B
    __shared__ ushort_t Pl[4][16 * 232];     // per-wave P[q][key]; also V stage

    const int bh = blockIdx.x;
    const int b = bh / NH, h = bh % NH;
    const int tid = threadIdx.x;
    const int w = tid >> 6, lane = tid & 63;
    const int quad = lane >> 4, l15 = lane & 15;
    const size_t base = (size_t)bh * (NN * HD);
    const ushort_t* kg = kbf + base;
    const ushort_t* vg = vbf + base;
    const ushort_t* qhg = qhi + base;
    const ushort_t* qlg = qlo + base;

    // 1) stage V row-major, coalesced b128 (rows >=197 zeroed)
    ushort_t* Vstage = &Pl[0][0];            // 208*64 = 13312 <= 14848 avail
    for (int idx = tid; idx < NP * 8; idx += 256) {
        int row = idx >> 3, ch = idx & 7;
        uint4 val = {0u, 0u, 0u, 0u};
        if (row < NN) val = *(const uint4*)(vg + (size_t)row * HD + ch * 8);
        *(uint4*)&Vstage[row * HD + ch * 8] = val;
    }
    __syncthreads();

    // 2) transpose LDS->LDS into Vt[d][key] (keys 208..231 zeroed)
    for (int task = tid; task < 64 * 29; task += 256) {
        int d = task & 63, kc = task >> 6;
        ushort_t tmp[8];
        #pragma unroll
        for (int j = 0; j < 8; j++) {
            int key = kc * 8 + j;
            tmp[j] = (key < NP) ? Vstage[key * HD + d] : (ushort_t)0;
        }
        uint4 u;
        u.x = (unsigned)tmp[0] | ((unsigned)tmp[1] << 16);
        u.y = (unsigned)tmp[2] | ((unsigned)tmp[3] << 16);
        u.z = (unsigned)tmp[4] | ((unsigned)tmp[5] << 16);
        u.w = (unsigned)tmp[6] | ((unsigned)tmp[7] << 16);
        *(uint4*)&Vt[d * 232 + kc * 8] = u;
    }
    __syncthreads();                         // Vt ready; Pl free for P use

    const int worker = blockIdx.y * 4 + w;   // 0..7

    #pragma unroll
    for (int rep = 0; rep < 2; rep++) {
        int qt = worker + rep * 8;
        if (qt > 12) break;
        const int q0 = qt * 16;

        int qrow = q0 + l15; if (qrow > NN - 1) qrow = NN - 1;
        U128 qh0, qh1, ql0, ql1;
        qh0.u = *(const uint4*)(qhg + (size_t)qrow * HD + quad * 8);
        qh1.u = *(const uint4*)(qhg + (size_t)qrow * HD + 32 + quad * 8);
        ql0.u = *(const uint4*)(qlg + (size_t)qrow * HD + quad * 8);
        ql1.u = *(const uint4*)(qlg + (size_t)qrow * HD + 32 + quad * 8);

        f32x4 S[13];
        #pragma unroll
        for (int kt = 0; kt < 13; kt++) {
            #pragma unroll
            for (int r = 0; r < 4; r++)
                S[kt][r] = biasM[((size_t)h * NP + (q0 + quad * 4 + r)) * NP + kt * 16 + l15];
        }

        #pragma unroll
        for (int kt = 0; kt < 13; kt++) {
            int krow = kt * 16 + l15; if (krow > NN - 1) krow = NN - 1;
            U128 k0, k1;
            k0.u = *(const uint4*)(kg + (size_t)krow * HD + quad * 8);
            k1.u = *(const uint4*)(kg + (size_t)krow * HD + 32 + quad * 8);
            S[kt] = __builtin_amdgcn_mfma_f32_16x16x32_bf16(qh0.s, k0.s, S[kt], 0, 0, 0);
            S[kt] = __builtin_amdgcn_mfma_f32_16x16x32_bf16(qh1.s, k1.s, S[kt], 0, 0, 0);
            S[kt] = __builtin_amdgcn_mfma_f32_16x16x32_bf16(ql0.s, k0.s, S[kt], 0, 0, 0);
            S[kt] = __builtin_amdgcn_mfma_f32_16x16x32_bf16(ql1.s, k1.s, S[kt], 0, 0, 0);
        }

        ushort_t* P = Pl[w];
        #pragma unroll
        for (int r = 0; r < 4; r++) {
            float mx = S[0][r];
            #pragma unroll
            for (int kt = 1; kt < 13; kt++) mx = fmaxf(mx, S[kt][r]);
            mx = fmaxf(mx, __shfl_xor(mx, 1));
            mx = fmaxf(mx, __shfl_xor(mx, 2));
            mx = fmaxf(mx, __shfl_xor(mx, 4));
            mx = fmaxf(mx, __shfl_xor(mx, 8));
            float sum = 0.f;
            #pragma unroll
            for (int kt = 0; kt < 13; kt++) {
                float e = __expf(S[kt][r] - mx);
                S[kt][r] = e;
                sum += e;
            }
            sum += __shfl_xor(sum, 1);
            sum += __shfl_xor(sum, 2);
            sum += __shfl_xor(sum, 4);
            sum += __shfl_xor(sum, 8);
            float inv = 1.0f / sum;
            int prow = quad * 4 + r;
            #pragma unroll
            for (int kt = 0; kt < 13; kt++)
                P[prow * 232 + kt * 16 + l15] = (ushort_t)bf16_rne(S[kt][r] * inv);
        }
        // zero P keys 208..231
        #pragma unroll
        for (int z = 0; z < 3; z++) {
            int idx = z * 64 + lane;
            int row = idx / 12, c = idx - row * 12;
            *(unsigned*)&P[row * 232 + NP + 2 * c] = 0u;
        }

        f32x4 O[4];
        f32x4 z4 = {0.f, 0.f, 0.f, 0.f};
        #pragma unroll
        for (int dt = 0; dt < 4; dt++) O[dt] = z4;
        #pragma unroll
        for (int ks = 0; ks < 7; ks++) {
            U128 pf;
            pf.u = *(const uint4*)&P[l15 * 232 + ks * 32 + quad * 8];
            #pragma unroll
            for (int dt = 0; dt < 4; dt++) {
                U128 vf;
                vf.u = *(const uint4*)&Vt[(dt * 16 + l15) * 232 + ks * 32 + quad * 8];
                O[dt] = __builtin_amdgcn_mfma_f32_16x16x32_bf16(pf.s, vf.s, O[dt], 0, 0, 0);
            }
        }

        #pragma unroll
        for (int dt = 0; dt < 4; dt++) {
            #pragma unroll
            for (int r = 0; r < 4; r++) {
                int q = q0 + quad * 4 + r;
                if (q < NN) {
                    float v = O[dt][r];
                    unsigned hi = bf16_rne(v);
                    unsigned lo = bf16_rne(v - __uint_as_float(hi << 16));
                    size_t off = ((size_t)b * NN + q) * K2 + h * HD + dt * 16 + l15;
                    ab2[off] = (ushort_t)hi;
                    ab2[off + NC] = (ushort_t)lo;
                }
            }
        }
    }
}

// ---------------------------------------------------------------------------
extern "C" void kernel_launch(void* const* d_in, const int* in_sizes, int n_in,
                              void* d_out, int out_size, void* d_ws, size_t ws_size,
                              hipStream_t stream)
{
    const float* x        = (const float*)d_in[0];
    const float* table    = (const float*)d_in[1];
    const float* w_qkv    = (const float*)d_in[2];
    const float* w_proj   = (const float*)d_in[3];
    const float* b_proj   = (const float*)d_in[4];
    const int*   rel_idx  = (const int*)d_in[5];
    float* out = (float*)d_out;

    ushort_t* x2  = (ushort_t*)d_ws;                        // MR*K2
    ushort_t* w2  = x2 + (size_t)MR * K2;                   // 2304*K2
    ushort_t* wp2 = w2 + (size_t)2304 * K2;                 // 768*K2
    ushort_t* ab2 = wp2 + (size_t)768 * K2;                 // MR*K2
    ushort_t* qhi = ab2 + (size_t)MR * K2;                  // SZQ each
    ushort_t* qlo = qhi + SZQ;
    ushort_t* kbf = qlo + SZQ;
    ushort_t* vbf = kbf + SZQ;
    float* biasM  = (float*)(vbf + SZQ);                    // 12*208*208

    const int cvt_quads = (MM + 2304 + 768) * 192;
    convert_all<<<(cvt_quads + 255) / 256, 256, 0, stream>>>(
        x, w_qkv, w_proj, x2, w2, wp2);
    bias_precompute<<<(NH * NP * NP + 255) / 256, 256, 0, stream>>>(table, rel_idx, biasM);

    gemm_qkv_mfma<<<dim3(99, 18), 256, 0, stream>>>(x2, w2, qhi, qlo, kbf, vbf);
    attn_mfma<<<dim3(NB * NH, 2), 256, 0, stream>>>(qhi, qlo, kbf, vbf, biasM, ab2);
    gemm_proj_mfma<<<dim3(99, 6), 256, 0, stream>>>(ab2, wp2, b_proj, out);
}

// Round 6
// 314.126 us; speedup vs baseline: 15.2199x; 1.1282x over previous
//
#include <hip/hip_runtime.h>

// Shapes: B=64, N=197, C=768, H=12, hd=64
// qkv GEMM: plain bf16 (K=768). proj GEMM: split-bf16 exact (hi|lo, K2=1536).
// Attention: MFMA flash-lite, bias pre-gathered in fragment layout.

#define NB   64
#define NN   197
#define NC   768
#define NH   12
#define HD   64
#define MM   (NB*NN)      // 12608
#define K2   1536
#define MR   12672        // 99*128
#define NP   208          // 13*16
#define SZQ  ((size_t)NB * NH * NN * HD)

typedef unsigned short ushort_t;
typedef __attribute__((ext_vector_type(8))) short short8;
typedef __attribute__((ext_vector_type(4))) float f32x4;
union U128 { uint4 u; short8 s; };

__device__ __forceinline__ unsigned bf16_rne(float f) {
    unsigned u = __float_as_uint(f);
    return (u + 0x7fffu + ((u >> 16) & 1u)) >> 16;
}

__device__ __forceinline__ void gld16(unsigned short* lds, const unsigned short* g) {
    __builtin_amdgcn_global_load_lds(
        (const __attribute__((address_space(1))) void*)g,
        (__attribute__((address_space(3))) void*)lds, 16, 0, 0);
}

// ---------------------------------------------------------------------------
// Converts: x -> xh (hi only), w_qkv -> wh (hi only), w_proj -> wp2 (hi|lo)
// ---------------------------------------------------------------------------
__global__ __launch_bounds__(256) void convert_all(
    const float* __restrict__ x, const float* __restrict__ w_qkv,
    const float* __restrict__ w_proj,
    ushort_t* __restrict__ xh, ushort_t* __restrict__ wh,
    ushort_t* __restrict__ wp2)
{
    int idx = blockIdx.x * 256 + threadIdx.x;
    if (idx >= (MM + 2304 + 768) * 192) return;
    int r = idx / 192;
    int c = (idx - r * 192) * 4;
    const float* src;
    ushort_t* dsth;
    bool want_lo = false;
    ushort_t* dstl = nullptr;
    if (r < MM) {
        src = x + (size_t)r * NC; dsth = xh + (size_t)r * NC + c;
    } else if (r < MM + 2304) {
        int rr = r - MM;
        src = w_qkv + (size_t)rr * NC; dsth = wh + (size_t)rr * NC + c;
    } else {
        int rr = r - MM - 2304;
        src = w_proj + (size_t)rr * NC;
        dsth = wp2 + (size_t)rr * K2 + c;
        dstl = dsth + NC;
        want_lo = true;
    }
    float4 f = *(const float4*)(src + c);
    unsigned h0 = bf16_rne(f.x), h1 = bf16_rne(f.y), h2 = bf16_rne(f.z), h3 = bf16_rne(f.w);
    ushort4 hv = { (ushort_t)h0, (ushort_t)h1, (ushort_t)h2, (ushort_t)h3 };
    *(ushort4*)dsth = hv;
    if (want_lo) {
        float r0 = f.x - __uint_as_float(h0 << 16);
        float r1 = f.y - __uint_as_float(h1 << 16);
        float r2 = f.z - __uint_as_float(h2 << 16);
        float r3 = f.w - __uint_as_float(h3 << 16);
        ushort4 lv = { (ushort_t)bf16_rne(r0), (ushort_t)bf16_rne(r1),
                       (ushort_t)bf16_rne(r2), (ushort_t)bf16_rne(r3) };
        *(ushort4*)dstl = lv;
    }
}

// ---------------------------------------------------------------------------
// biasP in MFMA C-fragment layout: [h][qt][kt][quad][l15][r] f32.
// Lane (quad,l15) loads float4 -> S rows quad*4+r, col kt*16+l15.
// ---------------------------------------------------------------------------
__global__ __launch_bounds__(256) void bias_precompute(
    const float* __restrict__ table, const int* __restrict__ rel_index,
    float* __restrict__ biasP)
{
    int i = blockIdx.x * 256 + threadIdx.x;
    if (i >= NH * 13 * 13 * 256) return;
    int r = i & 3, l15 = (i >> 2) & 15, quad = (i >> 6) & 3;
    int t = i >> 8;
    int kt = t % 13; int t2 = t / 13;
    int qt = t2 % 13; int h = t2 / 13;
    int n = qt * 16 + quad * 4 + r;
    int m = kt * 16 + l15;
    float v = -1e30f;
    if (n < NN && m < NN) v = table[rel_index[n * NN + m] * NH + h];
    biasP[i] = v;
}

// ---------------------------------------------------------------------------
// bf16 MFMA mainloop; strides + kiters parameterized.
// ---------------------------------------------------------------------------
__device__ __forceinline__ void gemm_mainloop(
    const ushort_t* __restrict__ A2, int sA,
    const ushort_t* __restrict__ B2, int sB,
    int m0, int n0, int kiters, ushort_t* Abuf, ushort_t* Bbuf, f32x4 acc[4][4])
{
    const int tid = threadIdx.x;
    const int w = tid >> 6, lane = tid & 63;
    const int wm = w & 1, wn = w >> 1;
    const int lr = lane >> 3, lc = lane & 7;
    const int gch = lc ^ lr;

    const ushort_t* Ag = A2 + (size_t)(m0 + w * 32 + lr) * sA + gch * 8;
    const ushort_t* Bg = B2 + (size_t)(n0 + w * 32 + lr) * sB + gch * 8;
    ushort_t* Al = Abuf + (w * 32) * 64;
    ushort_t* Bl = Bbuf + (w * 32) * 64;

    int aoff[4], boff[4];
    const int quad = lane >> 4, l15 = lane & 15;
    #pragma unroll
    for (int t = 0; t < 4; t++) {
        int ra = wm * 64 + t * 16 + l15;
        aoff[t] = ra * 64 + ((quad ^ (ra & 7)) << 3);
        int rb = wn * 64 + t * 16 + l15;
        boff[t] = rb * 64 + ((quad ^ (rb & 7)) << 3);
    }

    for (int ks = 0; ks < kiters; ks++) {
        __syncthreads();
        #pragma unroll
        for (int it = 0; it < 4; it++) {
            gld16(Al + it * 8 * 64, Ag + (size_t)it * 8 * sA);
            gld16(Bl + it * 8 * 64, Bg + (size_t)it * 8 * sB);
        }
        __syncthreads();
        #pragma unroll
        for (int k0 = 0; k0 < 2; k0++) {
            U128 af[4], bf[4];
            #pragma unroll
            for (int t = 0; t < 4; t++) {
                af[t].u = *(const uint4*)&Abuf[aoff[t] ^ (k0 << 5)];
                bf[t].u = *(const uint4*)&Bbuf[boff[t] ^ (k0 << 5)];
            }
            #pragma unroll
            for (int i = 0; i < 4; i++)
                #pragma unroll
                for (int j = 0; j < 4; j++)
                    acc[i][j] = __builtin_amdgcn_mfma_f32_16x16x32_bf16(
                        af[i].s, bf[j].s, acc[i][j], 0, 0, 0);
        }
        Ag += 64; Bg += 64;
    }
}

// GEMM1: xh[MR,768] * wh[2304,768]^T -> qbf (scaled), kbf, vbf (bf16 [bh][n][d])
// grid (18, 99): n-tiles fastest -> A-slice L2/L3-hot across its 18 consumers.
__global__ __launch_bounds__(256) void gemm_qkv_mfma(
    const ushort_t* __restrict__ A2, const ushort_t* __restrict__ B2,
    ushort_t* __restrict__ qbf, ushort_t* __restrict__ kbf,
    ushort_t* __restrict__ vbf)
{
    __shared__ ushort_t Abuf[128 * 64];
    __shared__ ushort_t Bbuf[128 * 64];
    f32x4 acc[4][4];
    f32x4 z = {0.f, 0.f, 0.f, 0.f};
    #pragma unroll
    for (int i = 0; i < 4; i++)
        #pragma unroll
        for (int j = 0; j < 4; j++) acc[i][j] = z;

    const int m0 = blockIdx.y * 128, n0 = blockIdx.x * 128;
    gemm_mainloop(A2, NC, B2, NC, m0, n0, 12, Abuf, Bbuf, acc);

    const int tid = threadIdx.x;
    const int w = tid >> 6, lane = tid & 63;
    const int wm = w & 1, wn = w >> 1;
    const int quad = lane >> 4, l15 = lane & 15;

    // hoist row decomposition (16 div/mod instead of 64)
    size_t baseo[4][4];
    bool valid[4][4];
    #pragma unroll
    for (int mt = 0; mt < 4; mt++) {
        #pragma unroll
        for (int r = 0; r < 4; r++) {
            int m = m0 + wm * 64 + mt * 16 + quad * 4 + r;
            valid[mt][r] = (m < MM);
            int mc = valid[mt][r] ? m : 0;
            int b_ = mc / NN, n_ = mc - b_ * NN;
            baseo[mt][r] = ((size_t)b_ * NH * NN + n_) * HD;
        }
    }
    #pragma unroll
    for (int nt = 0; nt < 4; nt++) {
        int c0 = n0 + wn * 64 + nt * 16;
        int tq = c0 / NC;
        int wi = c0 - tq * NC;
        int hh = wi >> 6;
        int d0 = (wi & 63) + l15;
        ushort_t* dst = (tq == 0) ? qbf : (tq == 1) ? kbf : vbf;
        float scale = (tq == 0) ? 0.125f : 1.0f;
        size_t hoff = (size_t)hh * (NN * HD) + d0;
        #pragma unroll
        for (int mt = 0; mt < 4; mt++) {
            #pragma unroll
            for (int r = 0; r < 4; r++) {
                if (valid[mt][r])
                    dst[baseo[mt][r] + hoff] = (ushort_t)bf16_rne(acc[mt][nt][r] * scale);
            }
        }
    }
}

// GEMM2: ab2[MR,K2] * wp2[768,K2]^T + bias -> out fp32 (exact). grid (6,99).
__global__ __launch_bounds__(256) void gemm_proj_mfma(
    const ushort_t* __restrict__ A2, const ushort_t* __restrict__ B2,
    const float* __restrict__ bias, float* __restrict__ out)
{
    __shared__ ushort_t Abuf[128 * 64];
    __shared__ ushort_t Bbuf[128 * 64];
    f32x4 acc[4][4];
    f32x4 z = {0.f, 0.f, 0.f, 0.f};
    #pragma unroll
    for (int i = 0; i < 4; i++)
        #pragma unroll
        for (int j = 0; j < 4; j++) acc[i][j] = z;

    const int m0 = blockIdx.y * 128, n0 = blockIdx.x * 128;
    gemm_mainloop(A2, K2, B2, K2, m0, n0, 24, Abuf, Bbuf, acc);

    const int tid = threadIdx.x;
    const int w = tid >> 6, lane = tid & 63;
    const int wm = w & 1, wn = w >> 1;
    const int quad = lane >> 4, l15 = lane & 15;
    #pragma unroll
    for (int nt = 0; nt < 4; nt++) {
        int col = n0 + wn * 64 + nt * 16 + l15;
        float bi = bias[col];
        #pragma unroll
        for (int mt = 0; mt < 4; mt++) {
            #pragma unroll
            for (int r = 0; r < 4; r++) {
                int m = m0 + wm * 64 + mt * 16 + quad * 4 + r;
                if (m < MM)
                    out[(size_t)m * NC + col] = acc[mt][nt][r] + bi;
            }
        }
    }
}

// ---------------------------------------------------------------------------
// MFMA attention. grid (768, 2) x 256 threads (4 waves).
// Q plain bf16 (2 MFMAs/kt). Bias from biasP via one float4/kt. O epilogue
// transposed through wave-private LDS -> b128 global stores.
// ---------------------------------------------------------------------------
__global__ __launch_bounds__(256) void attn_mfma(
    const ushort_t* __restrict__ qbf, const ushort_t* __restrict__ kbf,
    const ushort_t* __restrict__ vbf, const float* __restrict__ biasP,
    ushort_t* __restrict__ ab2)
{
    __shared__ ushort_t Vt[64 * 232];        // Vt[d][key], 29696 B
    __shared__ ushort_t Pl[4][16 * 232];     // per-wave P / V-stage / O-transpose

    const int bh = blockIdx.x;
    const int b = bh / NH, h = bh % NH;
    const int tid = threadIdx.x;
    const int w = tid >> 6, lane = tid & 63;
    const int quad = lane >> 4, l15 = lane & 15;
    const size_t base = (size_t)bh * (NN * HD);
    const ushort_t* kg = kbf + base;
    const ushort_t* vg = vbf + base;
    const ushort_t* qg = qbf + base;

    // stage V row-major coalesced, then LDS->LDS transpose into Vt
    ushort_t* Vstage = &Pl[0][0];            // 208*64 = 13312 <= 14848
    for (int idx = tid; idx < NP * 8; idx += 256) {
        int row = idx >> 3, ch = idx & 7;
        uint4 val = {0u, 0u, 0u, 0u};
        if (row < NN) val = *(const uint4*)(vg + (size_t)row * HD + ch * 8);
        *(uint4*)&Vstage[row * HD + ch * 8] = val;
    }
    __syncthreads();
    for (int task = tid; task < 64 * 29; task += 256) {
        int d = task & 63, kc = task >> 6;
        ushort_t tmp[8];
        #pragma unroll
        for (int j = 0; j < 8; j++) {
            int key = kc * 8 + j;
            tmp[j] = (key < NP) ? Vstage[key * HD + d] : (ushort_t)0;
        }
        uint4 u;
        u.x = (unsigned)tmp[0] | ((unsigned)tmp[1] << 16);
        u.y = (unsigned)tmp[2] | ((unsigned)tmp[3] << 16);
        u.z = (unsigned)tmp[4] | ((unsigned)tmp[5] << 16);
        u.w = (unsigned)tmp[6] | ((unsigned)tmp[7] << 16);
        *(uint4*)&Vt[d * 232 + kc * 8] = u;
    }
    __syncthreads();                         // Vt ready; Pl free

    const int worker = blockIdx.y * 4 + w;   // 0..7

    #pragma unroll
    for (int rep = 0; rep < 2; rep++) {
        int qt = worker + rep * 8;
        if (qt > 12) break;
        const int q0 = qt * 16;

        int qrow = q0 + l15; if (qrow > NN - 1) qrow = NN - 1;
        U128 qf0, qf1;
        qf0.u = *(const uint4*)(qg + (size_t)qrow * HD + quad * 8);
        qf1.u = *(const uint4*)(qg + (size_t)qrow * HD + 32 + quad * 8);

        // S init from biasP: one coalesced float4 per kt
        f32x4 S[13];
        const float* bp = biasP + ((size_t)(h * 13 + qt) * 13) * 256 + (quad << 6) + (l15 << 2);
        #pragma unroll
        for (int kt = 0; kt < 13; kt++) {
            float4 bv = *(const float4*)(bp + kt * 256);
            S[kt][0] = bv.x; S[kt][1] = bv.y; S[kt][2] = bv.z; S[kt][3] = bv.w;
        }

        // QK^T: 2 MFMAs per kt (Q plain bf16)
        #pragma unroll
        for (int kt = 0; kt < 13; kt++) {
            int krow = kt * 16 + l15; if (krow > NN - 1) krow = NN - 1;
            U128 k0, k1;
            k0.u = *(const uint4*)(kg + (size_t)krow * HD + quad * 8);
            k1.u = *(const uint4*)(kg + (size_t)krow * HD + 32 + quad * 8);
            S[kt] = __builtin_amdgcn_mfma_f32_16x16x32_bf16(qf0.s, k0.s, S[kt], 0, 0, 0);
            S[kt] = __builtin_amdgcn_mfma_f32_16x16x32_bf16(qf1.s, k1.s, S[kt], 0, 0, 0);
        }

        // softmax (rows quad*4+r over 16 l15 lanes x 13 tiles)
        ushort_t* P = Pl[w];
        #pragma unroll
        for (int r = 0; r < 4; r++) {
            float mx = S[0][r];
            #pragma unroll
            for (int kt = 1; kt < 13; kt++) mx = fmaxf(mx, S[kt][r]);
            mx = fmaxf(mx, __shfl_xor(mx, 1));
            mx = fmaxf(mx, __shfl_xor(mx, 2));
            mx = fmaxf(mx, __shfl_xor(mx, 4));
            mx = fmaxf(mx, __shfl_xor(mx, 8));
            float sum = 0.f;
            #pragma unroll
            for (int kt = 0; kt < 13; kt++) {
                float e = __expf(S[kt][r] - mx);
                S[kt][r] = e;
                sum += e;
            }
            sum += __shfl_xor(sum, 1);
            sum += __shfl_xor(sum, 2);
            sum += __shfl_xor(sum, 4);
            sum += __shfl_xor(sum, 8);
            float inv = 1.0f / sum;
            int prow = quad * 4 + r;
            #pragma unroll
            for (int kt = 0; kt < 13; kt++)
                P[prow * 232 + kt * 16 + l15] = (ushort_t)bf16_rne(S[kt][r] * inv);
        }
        // zero P keys 208..231
        #pragma unroll
        for (int z = 0; z < 3; z++) {
            int idx = z * 64 + lane;
            int row = idx / 12, c = idx - row * 12;
            *(unsigned*)&P[row * 232 + NP + 2 * c] = 0u;
        }

        // PV
        f32x4 O[4];
        f32x4 z4 = {0.f, 0.f, 0.f, 0.f};
        #pragma unroll
        for (int dt = 0; dt < 4; dt++) O[dt] = z4;
        #pragma unroll
        for (int ks = 0; ks < 7; ks++) {
            U128 pf;
            pf.u = *(const uint4*)&P[l15 * 232 + ks * 32 + quad * 8];
            #pragma unroll
            for (int dt = 0; dt < 4; dt++) {
                U128 vf;
                vf.u = *(const uint4*)&Vt[(dt * 16 + l15) * 232 + ks * 32 + quad * 8];
                O[dt] = __builtin_amdgcn_mfma_f32_16x16x32_bf16(pf.s, vf.s, O[dt], 0, 0, 0);
            }
        }

        // epilogue: transpose O through wave-private LDS, emit b128 hi|lo
        float* Osh = (float*)&Pl[w][0];      // stride 68 floats (16B-aligned rows)
        #pragma unroll
        for (int dt = 0; dt < 4; dt++)
            #pragma unroll
            for (int r = 0; r < 4; r++)
                Osh[(quad * 4 + r) * 68 + dt * 16 + l15] = O[dt][r];
        int orow = lane >> 2;
        int d0 = (lane & 3) << 4;
        int q = q0 + orow;
        if (q < NN) {
            unsigned hiw[8], low[8];
            #pragma unroll
            for (int k4 = 0; k4 < 4; k4++) {
                float4 f = *(const float4*)&Osh[orow * 68 + d0 + k4 * 4];
                unsigned h0 = bf16_rne(f.x), h1 = bf16_rne(f.y);
                unsigned h2 = bf16_rne(f.z), h3 = bf16_rne(f.w);
                hiw[k4 * 2]     = h0 | (h1 << 16);
                hiw[k4 * 2 + 1] = h2 | (h3 << 16);
                unsigned l0 = bf16_rne(f.x - __uint_as_float(h0 << 16));
                unsigned l1 = bf16_rne(f.y - __uint_as_float(h1 << 16));
                unsigned l2 = bf16_rne(f.z - __uint_as_float(h2 << 16));
                unsigned l3 = bf16_rne(f.w - __uint_as_float(h3 << 16));
                low[k4 * 2]     = l0 | (l1 << 16);
                low[k4 * 2 + 1] = l2 | (l3 << 16);
            }
            size_t baseo = ((size_t)b * NN + q) * K2 + h * HD + d0;
            uint4 hA = {hiw[0], hiw[1], hiw[2], hiw[3]};
            uint4 hB = {hiw[4], hiw[5], hiw[6], hiw[7]};
            uint4 lA = {low[0], low[1], low[2], low[3]};
            uint4 lB = {low[4], low[5], low[6], low[7]};
            *(uint4*)&ab2[baseo] = hA;
            *(uint4*)&ab2[baseo + 8] = hB;
            *(uint4*)&ab2[baseo + NC] = lA;
            *(uint4*)&ab2[baseo + NC + 8] = lB;
        }
    }
}

// ---------------------------------------------------------------------------
extern "C" void kernel_launch(void* const* d_in, const int* in_sizes, int n_in,
                              void* d_out, int out_size, void* d_ws, size_t ws_size,
                              hipStream_t stream)
{
    const float* x        = (const float*)d_in[0];
    const float* table    = (const float*)d_in[1];
    const float* w_qkv    = (const float*)d_in[2];
    const float* w_proj   = (const float*)d_in[3];
    const float* b_proj   = (const float*)d_in[4];
    const int*   rel_idx  = (const int*)d_in[5];
    float* out = (float*)d_out;

    ushort_t* xh  = (ushort_t*)d_ws;                        // MR*768
    ushort_t* wh  = xh + (size_t)MR * NC;                   // 2304*768
    ushort_t* wp2 = wh + (size_t)2304 * NC;                 // 768*1536
    ushort_t* ab2 = wp2 + (size_t)768 * K2;                 // MR*1536
    ushort_t* qbf = ab2 + (size_t)MR * K2;                  // SZQ each
    ushort_t* kbf = qbf + SZQ;
    ushort_t* vbf = kbf + SZQ;
    float* biasP  = (float*)(vbf + SZQ);                    // 12*13*13*256 f32

    const int cvt_quads = (MM + 2304 + 768) * 192;
    convert_all<<<(cvt_quads + 255) / 256, 256, 0, stream>>>(
        x, w_qkv, w_proj, xh, wh, wp2);
    bias_precompute<<<(NH * 13 * 13 * 256 + 255) / 256, 256, 0, stream>>>(
        table, rel_idx, biasP);

    gemm_qkv_mfma<<<dim3(18, 99), 256, 0, stream>>>(xh, wh, qbf, kbf, vbf);
    attn_mfma<<<dim3(NB * NH, 2), 256, 0, stream>>>(qbf, kbf, vbf, biasP, ab2);
    gemm_proj_mfma<<<dim3(6, 99), 256, 0, stream>>>(ab2, wp2, b_proj, out);
}